// Round 9
// baseline (824.920 us; speedup 1.0000x reference)
//
#include <hip/hip_runtime.h>
#include <math.h>

// ---------------------------------------------------------------------------
// Problem constants
// ---------------------------------------------------------------------------
#define NN 50000          // nodes
#define NE 800000         // edges (before self loops)
#define NEP (NE + NN)     // edges incl self loops
#define NGR 64            // graphs
#define NHEAD 8
#define MPAD 50048        // 391 * 128
#define DEG_CAPW 64       // per-wave LDS alpha slab (edges); exact fallback beyond

typedef short short8 __attribute__((ext_vector_type(8)));
typedef float floatx4 __attribute__((ext_vector_type(4)));
typedef unsigned uintx4 __attribute__((ext_vector_type(4)));

__device__ inline float bf2f(short s) {
    union { unsigned u; float f; } v;
    v.u = ((unsigned)(unsigned short)s) << 16;
    return v.f;
}
__device__ inline float bf2f_lo(unsigned p) {
    union { unsigned u; float f; } v; v.u = p << 16; return v.f;
}
__device__ inline float bf2f_hi(unsigned p) {
    union { unsigned u; float f; } v; v.u = p & 0xffff0000u; return v.f;
}
__device__ inline short f2bf(float f) {
    union { float f; unsigned u; } v; v.f = f;
    unsigned r = v.u + 0x7fffu + ((v.u >> 16) & 1u);   // RNE
    return (short)(r >> 16);
}

// async global->LDS, 16 B per lane; lds dst = wave-uniform base + lane*16
__device__ inline void gl_lds16(const short* g, short* l) {
    __builtin_amdgcn_global_load_lds(
        (const __attribute__((address_space(1))) unsigned int*)g,
        (__attribute__((address_space(3))) unsigned int*)l, 16, 0, 0);
}

// ---------------------------------------------------------------------------
// CSR build (dst-major). Edge e<NE: src=ei[e], dst=ei[NE+e]; else self loop.
// ---------------------------------------------------------------------------
__global__ void count_deg(const int* __restrict__ ei, int* __restrict__ deg) {
    int e = blockIdx.x * 256 + threadIdx.x;
    if (e >= NEP) return;
    int d = (e < NE) ? ei[NE + e] : (e - NE);
    atomicAdd(&deg[d], 1);
}

__global__ __launch_bounds__(1024) void scan_local(const int* __restrict__ deg,
                                                   int* __restrict__ out,
                                                   int* __restrict__ bsum, int n) {
    __shared__ int sd[1024];
    int b = blockIdx.x, t = threadIdx.x;
    int i = b * 1024 + t;
    int v = (i < n) ? deg[i] : 0;
    sd[t] = v;
    __syncthreads();
    for (int off = 1; off < 1024; off <<= 1) {
        int tmp = (t >= off) ? sd[t - off] : 0;
        __syncthreads();
        sd[t] += tmp;
        __syncthreads();
    }
    if (i < n) out[i] = sd[t] - v;          // exclusive
    if (t == 1023) bsum[b] = sd[1023];
}

__global__ void scan_bsum(int* __restrict__ bsum, int nb) {
    if (threadIdx.x == 0) {
        int s = 0;
        for (int i = 0; i < nb; i++) { int v = bsum[i]; bsum[i] = s; s += v; }
        bsum[nb] = s;
    }
}

__global__ void scan_add(int* __restrict__ row_ptr, int* __restrict__ cursor,
                         const int* __restrict__ bsum, int n, int nb) {
    int i = blockIdx.x * 256 + threadIdx.x;
    if (i < n) {
        int v = row_ptr[i] + bsum[i >> 10];
        row_ptr[i] = v;
        cursor[i] = v;
    } else if (i == n) {
        row_ptr[n] = bsum[nb];
    }
}

__global__ void scatter_edges(const int* __restrict__ ei, int* __restrict__ cursor,
                              int* __restrict__ srcs) {
    int e = blockIdx.x * 256 + threadIdx.x;
    if (e >= NEP) return;
    int s, d;
    if (e < NE) { s = ei[e]; d = ei[NE + e]; }
    else        { s = e - NE; d = e - NE; }
    int pos = atomicAdd(&cursor[d], 1);
    srcs[pos] = s;
}

// ---------------------------------------------------------------------------
// fp32 -> bf16 conversions
// ---------------------------------------------------------------------------
__global__ void conv_f2bf(const float* __restrict__ in, short* __restrict__ out, int n) {
    int i = blockIdx.x * 256 + threadIdx.x;
    if (i < n) out[i] = f2bf(in[i]);
}

__global__ void conv_x_pad4(const float* __restrict__ x, short* __restrict__ xb) {
    int i = blockIdx.x * 256 + threadIdx.x;          // one float4 per thread
    if (i >= MPAD * 32) return;
    int r = i >> 5;
    short4 o;
    if (r < NN) {
        float4 v = *(const float4*)&x[(size_t)i * 4];
        o.x = f2bf(v.x); o.y = f2bf(v.y); o.z = f2bf(v.z); o.w = f2bf(v.w);
    } else {
        o.x = o.y = o.z = o.w = 0;
    }
    *(short4*)&xb[(size_t)i * 4] = o;
}

// ---------------------------------------------------------------------------
// bf16 MFMA GEMM + fused es/ed epilogue, async global_load_lds staging.
// XOR-swizzled unpadded LDS, BK=64, 128x128 tile, 4 waves.
// ---------------------------------------------------------------------------
template <int C>
__global__ __launch_bounds__(256) void gemm_bf(const short* __restrict__ A,
                                               const short* __restrict__ B,
                                               short* __restrict__ Cout,
                                               const float* __restrict__ a_s,
                                               const float* __restrict__ a_d,
                                               float* __restrict__ es,
                                               float* __restrict__ ed,
                                               int K) {
    constexpr int Nc = 8 * C;
    constexpr int colTiles = Nc / 128;
    constexpr int JPH = C / 16;        // j-frags per head within a wave
    constexpr int HPW = 64 / C;        // heads fully covered by one wave
    __shared__ __align__(16) short As[128 * 64];
    __shared__ __align__(16) short Bs[128 * 64];
    int bx = blockIdx.x % colTiles;
    int by = blockIdx.x / colTiles;
    int row0 = by * 128, col0 = bx * 128;
    int t = threadIdx.x;
    int lane = t & 63, w = t >> 6;
    int wr = (w >> 1) * 64, wc = (w & 1) * 64;
    int lrow = lane & 15, lq = lane >> 4;

    int srow = lane >> 3;              // 0..7 row within group
    int kcsrc = (lane & 7) ^ srow;     // swizzled source k-chunk

    floatx4 acc[4][4];
#pragma unroll
    for (int i = 0; i < 4; i++)
#pragma unroll
        for (int j = 0; j < 4; j++) acc[i][j] = (floatx4)0.0f;

    for (int k0 = 0; k0 < K; k0 += 64) {
#pragma unroll
        for (int it = 0; it < 4; it++) {
            int r0 = w * 32 + it * 8;
            int r = r0 + srow;
            gl_lds16(&A[(size_t)(row0 + r) * K + k0 + kcsrc * 8], &As[r0 * 64]);
            gl_lds16(&B[(size_t)(col0 + r) * K + k0 + kcsrc * 8], &Bs[r0 * 64]);
        }
        __syncthreads();
#pragma unroll
        for (int kk = 0; kk < 2; kk++) {
            int slot = (kk * 4 + lq) ^ (lrow & 7);
            short8 af[4], bfr[4];
#pragma unroll
            for (int i = 0; i < 4; i++)
                af[i] = *(const short8*)&As[(wr + i * 16 + lrow) * 64 + slot * 8];
#pragma unroll
            for (int j = 0; j < 4; j++)
                bfr[j] = *(const short8*)&Bs[(wc + j * 16 + lrow) * 64 + slot * 8];
#pragma unroll
            for (int i = 0; i < 4; i++)
#pragma unroll
                for (int j = 0; j < 4; j++)
                    acc[i][j] = __builtin_amdgcn_mfma_f32_16x16x32_bf16(af[i], bfr[j], acc[i][j], 0, 0, 0);
        }
        __syncthreads();
    }

    // ---- C store
#pragma unroll
    for (int i = 0; i < 4; i++)
#pragma unroll
        for (int j = 0; j < 4; j++)
#pragma unroll
            for (int r = 0; r < 4; r++) {
                int row = row0 + wr + i * 16 + lq * 4 + r;
                int col = col0 + wc + j * 16 + lrow;
                Cout[(size_t)row * Nc + col] = f2bf(acc[i][j][r]);
            }

    // ---- fused es/ed epilogue
    float asv[4], adv[4];
#pragma unroll
    for (int j = 0; j < 4; j++) {
        int colA = col0 + wc + j * 16 + lrow;
        asv[j] = a_s[colA];
        adv[j] = a_d[colA];
    }
    int hb = (col0 + wc) / C;
#pragma unroll
    for (int i = 0; i < 4; i++)
#pragma unroll
        for (int r = 0; r < 4; r++) {
            float s_h[HPW], d_h[HPW];
#pragma unroll
            for (int hh = 0; hh < HPW; hh++) { s_h[hh] = 0.f; d_h[hh] = 0.f; }
#pragma unroll
            for (int j = 0; j < 4; j++) {
                s_h[j / JPH] = fmaf(acc[i][j][r], asv[j], s_h[j / JPH]);
                d_h[j / JPH] = fmaf(acc[i][j][r], adv[j], d_h[j / JPH]);
            }
#pragma unroll
            for (int hh = 0; hh < HPW; hh++) {
#pragma unroll
                for (int off = 1; off <= 8; off <<= 1) {
                    s_h[hh] += __shfl_xor(s_h[hh], off);
                    d_h[hh] += __shfl_xor(d_h[hh], off);
                }
            }
            if (lrow == 0) {
                int row = row0 + wr + i * 16 + lq * 4 + r;
                if (row < NN) {
#pragma unroll
                    for (int hh = 0; hh < HPW; hh++) {
                        es[row * 8 + hb + hh] = s_h[hh];
                        ed[row * 8 + hb + hh] = d_h[hh];
                    }
                }
            }
        }
}

// ---------------------------------------------------------------------------
// Attention — ONE WAVE PER NODE, wave-synchronous.
// Pass 1: online softmax, stash leaky-relu logits in per-wave LDS slab (8KB/blk).
// Fixup : slab -> normalized alpha in place.
// Pass 2: ds_read alpha + 16B h gather, U*EPI edges in flight (U=8 for C=64).
// ---------------------------------------------------------------------------
template <int C, bool ELU>
__global__ __launch_bounds__(256) void attn_wave(const short* __restrict__ h,
                                                 const float* __restrict__ es,
                                                 const float* __restrict__ ed,
                                                 const int* __restrict__ row_ptr,
                                                 const int* __restrict__ srcs,
                                                 const float* __restrict__ bias,
                                                 short* __restrict__ out) {
    constexpr int HC = NHEAD * C;
    constexpr int TPR = HC / 8;        // lanes covering one row: 64/32/16
    constexpr int EPI = 64 / TPR;      // edge groups per wave: 1/2/4
    constexpr int U = (EPI == 1) ? 8 : 4;   // unroll: U*EPI loads in flight
    __shared__ float lw[4][DEG_CAPW * NHEAD];
    int wave = threadIdx.x >> 6, lane = threadIdx.x & 63;
    float* lwW = lw[wave];
    int n = blockIdx.x * 4 + wave;     // grid = NN/4 exactly (NN%4==0)
    int start = row_ptr[n];
    int deg = row_ptr[n + 1] - start;
    int degc = deg < DEG_CAPW ? deg : DEG_CAPW;
    int hh1 = lane & 7;
    float edv = ed[n * 8 + hh1];

    // pass 1: online per-head softmax stats; stash logits (idx = k*8+head)
    float pm = -1e30f, ps = 0.f;
    for (int idx = lane; idx < deg * 8; idx += 64) {
        int s = srcs[start + (idx >> 3)];
        float e = es[s * 8 + hh1] + edv;
        e = e > 0.f ? e : 0.2f * e;
        if (idx < DEG_CAPW * 8) lwW[idx] = e;
        float mn = fmaxf(pm, e);
        ps = ps * __expf(pm - mn) + __expf(e - mn);
        pm = mn;
    }
#pragma unroll
    for (int off = 8; off <= 32; off <<= 1) {
        float mo = __shfl_xor(pm, off);
        float so = __shfl_xor(ps, off);
        float mn = fmaxf(pm, mo);
        ps = ps * __expf(pm - mn) + so * __expf(mo - mn);
        pm = mn;
    }
    float invd = 1.0f / ps;

    // fixup: slab logit -> normalized alpha (lane idx&7 == hh1)
    int m8 = degc * 8;
    for (int idx = lane; idx < m8; idx += 64)
        lwW[idx] = __expf(lwW[idx] - pm) * invd;
    __builtin_amdgcn_wave_barrier();
    __asm__ volatile("s_waitcnt lgkmcnt(0)" ::: "memory");

    // remap per-head state to pass-2 lane roles (for fallback only)
    int g = lane / TPR;
    int sub = lane & (TPR - 1);
    int c0 = sub * 8;
    int hh = c0 / C;                   // head of this lane's channel chunk
    float mh3 = __shfl(pm, hh);
    float iv3 = __shfl(invd, hh);
    float ed3 = __shfl(edv, hh);

    float acc[8];
#pragma unroll
    for (int j = 0; j < 8; j++) acc[j] = 0.f;

    // pass 2: U*EPI edges in flight
    int k = g;
    for (; k + (U - 1) * EPI < degc; k += U * EPI) {
        int ss[U];
        float ww[U];
#pragma unroll
        for (int u = 0; u < U; u++) {
            ss[u] = srcs[start + k + u * EPI];
            ww[u] = lwW[(k + u * EPI) * 8 + hh];
        }
        uintx4 hv[U];
#pragma unroll
        for (int u = 0; u < U; u++)
            hv[u] = *(const uintx4*)&h[(size_t)ss[u] * HC + c0];
#pragma unroll
        for (int u = 0; u < U; u++) {
#pragma unroll
            for (int j = 0; j < 4; j++) {
                acc[2 * j]     = fmaf(ww[u], bf2f_lo(hv[u][j]), acc[2 * j]);
                acc[2 * j + 1] = fmaf(ww[u], bf2f_hi(hv[u][j]), acc[2 * j + 1]);
            }
        }
    }
    for (; k < degc; k += EPI) {
        int s = srcs[start + k];
        float wv = lwW[k * 8 + hh];
        uintx4 hv = *(const uintx4*)&h[(size_t)s * HC + c0];
#pragma unroll
        for (int j = 0; j < 4; j++) {
            acc[2 * j]     = fmaf(wv, bf2f_lo(hv[j]), acc[2 * j]);
            acc[2 * j + 1] = fmaf(wv, bf2f_hi(hv[j]), acc[2 * j + 1]);
        }
    }
    if (deg > DEG_CAPW) {              // exact fallback (rarely/never taken)
        for (int kk = DEG_CAPW + g; kk < deg; kk += EPI) {
            int s = srcs[start + kk];
            float e = es[s * 8 + hh] + ed3;
            e = e > 0.f ? e : 0.2f * e;
            float wv = __expf(e - mh3) * iv3;
            uintx4 hv = *(const uintx4*)&h[(size_t)s * HC + c0];
#pragma unroll
            for (int j = 0; j < 4; j++) {
                acc[2 * j]     = fmaf(wv, bf2f_lo(hv[j]), acc[2 * j]);
                acc[2 * j + 1] = fmaf(wv, bf2f_hi(hv[j]), acc[2 * j + 1]);
            }
        }
    }
    if (EPI >= 2) {
#pragma unroll
        for (int j = 0; j < 8; j++) acc[j] += __shfl_xor(acc[j], 32);
    }
    if (EPI == 4) {
#pragma unroll
        for (int j = 0; j < 8; j++) acc[j] += __shfl_xor(acc[j], 16);
    }
    if (lane < TPR) {
        floatx4 b0 = *(const floatx4*)&bias[c0];
        floatx4 b1 = *(const floatx4*)&bias[c0 + 4];
        float bb[8] = {b0[0], b0[1], b0[2], b0[3], b1[0], b1[1], b1[2], b1[3]};
        unsigned pk[4];
#pragma unroll
        for (int j = 0; j < 4; j++) {
            float o0 = acc[2 * j] + bb[2 * j];
            float o1 = acc[2 * j + 1] + bb[2 * j + 1];
            if (ELU) {
                o0 = o0 > 0.f ? o0 : (__expf(o0) - 1.0f);
                o1 = o1 > 0.f ? o1 : (__expf(o1) - 1.0f);
            }
            pk[j] = ((unsigned)(unsigned short)f2bf(o0)) |
                    (((unsigned)(unsigned short)f2bf(o1)) << 16);
        }
        *(uintx4*)&out[(size_t)n * HC + c0] = *(uintx4*)pk;
    }
}

// ---------------------------------------------------------------------------
// Global mean pool: 64 graphs x 8 feature-chunks of 64; 4 row stripes/block.
// ---------------------------------------------------------------------------
__global__ __launch_bounds__(256) void pool_kernel(const short* __restrict__ h,
                                                   const int* __restrict__ batch,
                                                   float* __restrict__ gout) {
    __shared__ float red[256];
    int g = blockIdx.x >> 3;
    int fc = (blockIdx.x & 7) * 64;
    int lo = 0, hi = NN;
    while (lo < hi) { int mid = (lo + hi) >> 1; if (batch[mid] < g) lo = mid + 1; else hi = mid; }
    int s = lo;
    lo = 0; hi = NN;
    while (lo < hi) { int mid = (lo + hi) >> 1; if (batch[mid] < g + 1) lo = mid + 1; else hi = mid; }
    int e = lo;
    int t = threadIdx.x;
    int f = t & 63, stripe = t >> 6;
    float a = 0.f;
    for (int r = s + stripe; r < e; r += 4)
        a += bf2f(h[(size_t)r * 512 + fc + f]);
    red[t] = a;
    __syncthreads();
    if (t < 128) red[t] += red[t + 128];
    __syncthreads();
    if (t < 64) {
        float inv = 1.0f / fmaxf((float)(e - s), 1.0f);
        gout[g * 512 + fc + t] = (red[t] + red[t + 64]) * inv;
    }
}

// ---------------------------------------------------------------------------
// Final MLP: [64,512] -> elu(@lw1^T+lb1) -> @lw2^T+lb2 -> [64,2]
// ---------------------------------------------------------------------------
__global__ __launch_bounds__(64) void mlp_kernel(const float* __restrict__ g,
                                                 const float* __restrict__ lw1,
                                                 const float* __restrict__ lb1,
                                                 const float* __restrict__ lw2,
                                                 const float* __restrict__ lb2,
                                                 float* __restrict__ outp) {
    __shared__ float gv[512];
    __shared__ float y1[32];
    int b = blockIdx.x, t = threadIdx.x;
    for (int i = t; i < 512; i += 64) gv[i] = g[b * 512 + i];
    __syncthreads();
    if (t < 32) {
        float a = lb1[t];
        for (int k = 0; k < 512; k++) a = fmaf(gv[k], lw1[t * 512 + k], a);
        y1[t] = a > 0.f ? a : (__expf(a) - 1.0f);
    }
    __syncthreads();
    if (t < 2) {
        float a = lb2[t];
        for (int k = 0; k < 32; k++) a = fmaf(y1[k], lw2[t * 32 + k], a);
        outp[b * 2 + t] = a;
    }
}

// ---------------------------------------------------------------------------
// Launch
// ---------------------------------------------------------------------------
extern "C" void kernel_launch(void* const* d_in, const int* in_sizes, int n_in,
                              void* d_out, int out_size, void* d_ws, size_t ws_size,
                              hipStream_t stream) {
    (void)in_sizes; (void)n_in; (void)out_size; (void)ws_size;
    const float* x     = (const float*)d_in[0];
    const int*   ei    = (const int*)d_in[1];
    const int*   batch = (const int*)d_in[2];
    const float* W[4]  = {(const float*)d_in[3], (const float*)d_in[7],
                          (const float*)d_in[11], (const float*)d_in[15]};
    const float* As_[4] = {(const float*)d_in[4], (const float*)d_in[8],
                           (const float*)d_in[12], (const float*)d_in[16]};
    const float* Ad_[4] = {(const float*)d_in[5], (const float*)d_in[9],
                           (const float*)d_in[13], (const float*)d_in[17]};
    const float* Bi[4]  = {(const float*)d_in[6], (const float*)d_in[10],
                           (const float*)d_in[14], (const float*)d_in[18]};
    const float* lw1 = (const float*)d_in[19];
    const float* lb1 = (const float*)d_in[20];
    const float* lw2 = (const float*)d_in[21];
    const float* lb2 = (const float*)d_in[22];
    float* out = (float*)d_out;

    // workspace layout (bf16 buffers as short)
    short* Ab = (short*)d_ws;                      // [MPAD*512] activations
    short* Hb = Ab + (size_t)MPAD * 512;           // [MPAD*512] h = act @ W^T
    short* Wb = Hb + (size_t)MPAD * 512;           // bf16 weights
    short* Wb_[4] = {Wb, Wb + 65536, Wb + 196608, Wb + 229376};
    const int wsz[4] = {65536, 131072, 32768, 65536};
    float* esb  = (float*)(Wb + 294912);           // [NN*8]
    float* edb  = esb + NN * NHEAD;                // [NN*8]
    float* gbuf = edb + NN * NHEAD;                // [64*512]
    int* row_ptr = (int*)(gbuf + NGR * 512);       // [NN+1]
    int* cursor  = row_ptr + (NN + 1);             // [NN+1]
    int* srcs    = cursor + (NN + 1);              // [NEP]
    int* bsum    = srcs + NEP;                     // [64]

    const int nblk = (NN + 1023) / 1024;           // 49

    // ---- CSR build (shared by all 4 layers)
    hipMemsetAsync(cursor, 0, NN * sizeof(int), stream);
    count_deg<<<(NEP + 255) / 256, 256, 0, stream>>>(ei, cursor);
    scan_local<<<nblk, 1024, 0, stream>>>(cursor, row_ptr, bsum, NN);
    scan_bsum<<<1, 64, 0, stream>>>(bsum, nblk);
    scan_add<<<(NN + 256) / 256, 256, 0, stream>>>(row_ptr, cursor, bsum, NN, nblk);
    scatter_edges<<<(NEP + 255) / 256, 256, 0, stream>>>(ei, cursor, srcs);

    // ---- bf16 conversions
    conv_x_pad4<<<(MPAD * 32 + 255) / 256, 256, 0, stream>>>(x, Ab);
    for (int i = 0; i < 4; i++)
        conv_f2bf<<<(wsz[i] + 255) / 256, 256, 0, stream>>>(W[i], Wb_[i], wsz[i]);

    const int rowTiles = MPAD / 128;               // 391
    const int ag = NN / 4;                         // 12500 blocks, 4 nodes each

    // ---- layer 1: 128 -> 512 (C=64), ELU
    gemm_bf<64><<<rowTiles * 4, 256, 0, stream>>>(Ab, Wb_[0], Hb, As_[0], Ad_[0], esb, edb, 128);
    attn_wave<64, true><<<ag, 256, 0, stream>>>(Hb, esb, edb, row_ptr, srcs, Bi[0], Ab);

    // ---- layer 2: 512 -> 256 (C=32), ELU
    gemm_bf<32><<<rowTiles * 2, 256, 0, stream>>>(Ab, Wb_[1], Hb, As_[1], Ad_[1], esb, edb, 512);
    attn_wave<32, true><<<ag, 256, 0, stream>>>(Hb, esb, edb, row_ptr, srcs, Bi[1], Ab);

    // ---- layer 3: 256 -> 128 (C=16), ELU
    gemm_bf<16><<<rowTiles * 1, 256, 0, stream>>>(Ab, Wb_[2], Hb, As_[2], Ad_[2], esb, edb, 256);
    attn_wave<16, true><<<ag, 256, 0, stream>>>(Hb, esb, edb, row_ptr, srcs, Bi[2], Ab);

    // ---- layer 4: 128 -> 512 (C=64), no ELU
    gemm_bf<64><<<rowTiles * 4, 256, 0, stream>>>(Ab, Wb_[3], Hb, As_[3], Ad_[3], esb, edb, 128);
    attn_wave<64, false><<<ag, 256, 0, stream>>>(Hb, esb, edb, row_ptr, srcs, Bi[3], Ab);

    // ---- pool + MLP
    pool_kernel<<<NGR * 8, 256, 0, stream>>>(Ab, batch, gbuf);
    mlp_kernel<<<NGR, 64, 0, stream>>>(gbuf, lw1, lb1, lw2, lb2, out);
}

// Round 10
// 802.230 us; speedup vs baseline: 1.0283x; 1.0283x over previous
//
#include <hip/hip_runtime.h>
#include <math.h>

// ---------------------------------------------------------------------------
// Problem constants
// ---------------------------------------------------------------------------
#define NN 50000          // nodes
#define NE 800000         // edges (before self loops)
#define NEP (NE + NN)     // edges incl self loops
#define NGR 64            // graphs
#define NHEAD 8
#define MPAD 50048        // 391 * 128
#define DEG_CAPW 128      // per-wave LDS alpha slab (edges); exact fallback beyond

typedef short short8 __attribute__((ext_vector_type(8)));
typedef float floatx4 __attribute__((ext_vector_type(4)));
typedef unsigned uintx4 __attribute__((ext_vector_type(4)));

__device__ inline float bf2f(short s) {
    union { unsigned u; float f; } v;
    v.u = ((unsigned)(unsigned short)s) << 16;
    return v.f;
}
__device__ inline float bf2f_lo(unsigned p) {
    union { unsigned u; float f; } v; v.u = p << 16; return v.f;
}
__device__ inline float bf2f_hi(unsigned p) {
    union { unsigned u; float f; } v; v.u = p & 0xffff0000u; return v.f;
}
__device__ inline short f2bf(float f) {
    union { float f; unsigned u; } v; v.f = f;
    unsigned r = v.u + 0x7fffu + ((v.u >> 16) & 1u);   // RNE
    return (short)(r >> 16);
}

// async global->LDS, 16 B per lane; lds dst = wave-uniform base + lane*16
__device__ inline void gl_lds16(const short* g, short* l) {
    __builtin_amdgcn_global_load_lds(
        (const __attribute__((address_space(1))) unsigned int*)g,
        (__attribute__((address_space(3))) unsigned int*)l, 16, 0, 0);
}

// ---------------------------------------------------------------------------
// CSR build (dst-major). Edge e<NE: src=ei[e], dst=ei[NE+e]; else self loop.
// ---------------------------------------------------------------------------
__global__ void count_deg(const int* __restrict__ ei, int* __restrict__ deg) {
    int e = blockIdx.x * 256 + threadIdx.x;
    if (e >= NEP) return;
    int d = (e < NE) ? ei[NE + e] : (e - NE);
    atomicAdd(&deg[d], 1);
}

__global__ __launch_bounds__(1024) void scan_local(const int* __restrict__ deg,
                                                   int* __restrict__ out,
                                                   int* __restrict__ bsum, int n) {
    __shared__ int sd[1024];
    int b = blockIdx.x, t = threadIdx.x;
    int i = b * 1024 + t;
    int v = (i < n) ? deg[i] : 0;
    sd[t] = v;
    __syncthreads();
    for (int off = 1; off < 1024; off <<= 1) {
        int tmp = (t >= off) ? sd[t - off] : 0;
        __syncthreads();
        sd[t] += tmp;
        __syncthreads();
    }
    if (i < n) out[i] = sd[t] - v;          // exclusive
    if (t == 1023) bsum[b] = sd[1023];
}

__global__ void scan_bsum(int* __restrict__ bsum, int nb) {
    if (threadIdx.x == 0) {
        int s = 0;
        for (int i = 0; i < nb; i++) { int v = bsum[i]; bsum[i] = s; s += v; }
        bsum[nb] = s;
    }
}

__global__ void scan_add(int* __restrict__ row_ptr, int* __restrict__ cursor,
                         const int* __restrict__ bsum, int n, int nb) {
    int i = blockIdx.x * 256 + threadIdx.x;
    if (i < n) {
        int v = row_ptr[i] + bsum[i >> 10];
        row_ptr[i] = v;
        cursor[i] = v;
    } else if (i == n) {
        row_ptr[n] = bsum[nb];
    }
}

__global__ void scatter_edges(const int* __restrict__ ei, int* __restrict__ cursor,
                              int* __restrict__ srcs) {
    int e = blockIdx.x * 256 + threadIdx.x;
    if (e >= NEP) return;
    int s, d;
    if (e < NE) { s = ei[e]; d = ei[NE + e]; }
    else        { s = e - NE; d = e - NE; }
    int pos = atomicAdd(&cursor[d], 1);
    srcs[pos] = s;
}

// ---------------------------------------------------------------------------
// fp32 -> bf16 conversions
// ---------------------------------------------------------------------------
__global__ void conv_f2bf(const float* __restrict__ in, short* __restrict__ out, int n) {
    int i = blockIdx.x * 256 + threadIdx.x;
    if (i < n) out[i] = f2bf(in[i]);
}

__global__ void conv_x_pad4(const float* __restrict__ x, short* __restrict__ xb) {
    int i = blockIdx.x * 256 + threadIdx.x;          // one float4 per thread
    if (i >= MPAD * 32) return;
    int r = i >> 5;
    short4 o;
    if (r < NN) {
        float4 v = *(const float4*)&x[(size_t)i * 4];
        o.x = f2bf(v.x); o.y = f2bf(v.y); o.z = f2bf(v.z); o.w = f2bf(v.w);
    } else {
        o.x = o.y = o.z = o.w = 0;
    }
    *(short4*)&xb[(size_t)i * 4] = o;
}

// ---------------------------------------------------------------------------
// bf16 MFMA GEMM + fused es/ed epilogue, DOUBLE-BUFFERED async staging.
// C[MPAD,Nc](bf16) = A[MPAD,K](bf16) @ B[Nc,K](bf16)^T, Nc = 8*C.
// 128x128 tile, BK=64, 4 waves. Prefetch of tile k+1 is issued right after
// the barrier and flies during the MFMA phase of tile k; the next barrier's
// vmcnt(0) drain lands after the overlap window instead of stalling cold.
// LDS 4x16KB = 64KB -> 2 blocks/CU (GEMM grids are 391-1564 blocks).
// ---------------------------------------------------------------------------
template <int C>
__global__ __launch_bounds__(256) void gemm_bf(const short* __restrict__ A,
                                               const short* __restrict__ B,
                                               short* __restrict__ Cout,
                                               const float* __restrict__ a_s,
                                               const float* __restrict__ a_d,
                                               float* __restrict__ es,
                                               float* __restrict__ ed,
                                               int K) {
    constexpr int Nc = 8 * C;
    constexpr int colTiles = Nc / 128;
    constexpr int JPH = C / 16;        // j-frags per head within a wave
    constexpr int HPW = 64 / C;        // heads fully covered by one wave
    __shared__ __align__(16) short As[2][128 * 64];
    __shared__ __align__(16) short Bs[2][128 * 64];
    int bx = blockIdx.x % colTiles;
    int by = blockIdx.x / colTiles;
    int row0 = by * 128, col0 = bx * 128;
    int t = threadIdx.x;
    int lane = t & 63, w = t >> 6;
    int wr = (w >> 1) * 64, wc = (w & 1) * 64;
    int lrow = lane & 15, lq = lane >> 4;

    int srow = lane >> 3;              // 0..7 row within 8-row group
    int kcsrc = (lane & 7) ^ srow;     // swizzled source k-chunk

    floatx4 acc[4][4];
#pragma unroll
    for (int i = 0; i < 4; i++)
#pragma unroll
        for (int j = 0; j < 4; j++) acc[i][j] = (floatx4)0.0f;

    const int nIter = K >> 6;

    // initial stage into buffer 0
#pragma unroll
    for (int it = 0; it < 4; it++) {
        int r0 = w * 32 + it * 8;
        int r = r0 + srow;
        gl_lds16(&A[(size_t)(row0 + r) * K + kcsrc * 8], &As[0][r0 * 64]);
        gl_lds16(&B[(size_t)(col0 + r) * K + kcsrc * 8], &Bs[0][r0 * 64]);
    }

    for (int itk = 0; itk < nIter; itk++) {
        int cur = itk & 1;
        __syncthreads();               // drains vmcnt -> buffer `cur` ready
        if (itk + 1 < nIter) {         // prefetch next tile into other buffer
            int k0 = (itk + 1) << 6;
            int nxt = cur ^ 1;
#pragma unroll
            for (int it = 0; it < 4; it++) {
                int r0 = w * 32 + it * 8;
                int r = r0 + srow;
                gl_lds16(&A[(size_t)(row0 + r) * K + k0 + kcsrc * 8], &As[nxt][r0 * 64]);
                gl_lds16(&B[(size_t)(col0 + r) * K + k0 + kcsrc * 8], &Bs[nxt][r0 * 64]);
            }
        }
#pragma unroll
        for (int kk = 0; kk < 2; kk++) {
            int slot = (kk * 4 + lq) ^ (lrow & 7);
            short8 af[4], bfr[4];
#pragma unroll
            for (int i = 0; i < 4; i++)
                af[i] = *(const short8*)&As[cur][(wr + i * 16 + lrow) * 64 + slot * 8];
#pragma unroll
            for (int j = 0; j < 4; j++)
                bfr[j] = *(const short8*)&Bs[cur][(wc + j * 16 + lrow) * 64 + slot * 8];
#pragma unroll
            for (int i = 0; i < 4; i++)
#pragma unroll
                for (int j = 0; j < 4; j++)
                    acc[i][j] = __builtin_amdgcn_mfma_f32_16x16x32_bf16(af[i], bfr[j], acc[i][j], 0, 0, 0);
        }
    }

    // ---- C store (D layout: row=wr+i*16+lq*4+r, col=wc+j*16+lrow)
#pragma unroll
    for (int i = 0; i < 4; i++)
#pragma unroll
        for (int j = 0; j < 4; j++)
#pragma unroll
            for (int r = 0; r < 4; r++) {
                int row = row0 + wr + i * 16 + lq * 4 + r;
                int col = col0 + wc + j * 16 + lrow;
                Cout[(size_t)row * Nc + col] = f2bf(acc[i][j][r]);
            }

    // ---- fused es/ed epilogue (a_s flat [H*C] == abs col index)
    float asv[4], adv[4];
#pragma unroll
    for (int j = 0; j < 4; j++) {
        int colA = col0 + wc + j * 16 + lrow;
        asv[j] = a_s[colA];
        adv[j] = a_d[colA];
    }
    int hb = (col0 + wc) / C;
#pragma unroll
    for (int i = 0; i < 4; i++)
#pragma unroll
        for (int r = 0; r < 4; r++) {
            float s_h[HPW], d_h[HPW];
#pragma unroll
            for (int hh = 0; hh < HPW; hh++) { s_h[hh] = 0.f; d_h[hh] = 0.f; }
#pragma unroll
            for (int j = 0; j < 4; j++) {
                s_h[j / JPH] = fmaf(acc[i][j][r], asv[j], s_h[j / JPH]);
                d_h[j / JPH] = fmaf(acc[i][j][r], adv[j], d_h[j / JPH]);
            }
#pragma unroll
            for (int hh = 0; hh < HPW; hh++) {
#pragma unroll
                for (int off = 1; off <= 8; off <<= 1) {
                    s_h[hh] += __shfl_xor(s_h[hh], off);
                    d_h[hh] += __shfl_xor(d_h[hh], off);
                }
            }
            if (lrow == 0) {
                int row = row0 + wr + i * 16 + lq * 4 + r;
                if (row < NN) {
#pragma unroll
                    for (int hh = 0; hh < HPW; hh++) {
                        es[row * 8 + hb + hh] = s_h[hh];
                        ed[row * 8 + hb + hh] = d_h[hh];
                    }
                }
            }
        }
}

// ---------------------------------------------------------------------------
// Attention — ONE WAVE PER NODE, wave-synchronous (R8 config: CAPW=128, U=4).
// Pass 1: online softmax, stash leaky-relu logits in per-wave LDS slab.
// Fixup : slab -> normalized alpha in place.
// Pass 2: ds_read alpha + 16B h gather, U*EPI edges in flight.
// ---------------------------------------------------------------------------
template <int C, bool ELU>
__global__ __launch_bounds__(256) void attn_wave(const short* __restrict__ h,
                                                 const float* __restrict__ es,
                                                 const float* __restrict__ ed,
                                                 const int* __restrict__ row_ptr,
                                                 const int* __restrict__ srcs,
                                                 const float* __restrict__ bias,
                                                 short* __restrict__ out) {
    constexpr int HC = NHEAD * C;
    constexpr int TPR = HC / 8;        // lanes covering one row: 64/32/16
    constexpr int EPI = 64 / TPR;      // edge groups per wave: 1/2/4
    constexpr int U = (EPI == 1) ? 4 : 2;   // unroll: U*EPI loads in flight
    __shared__ float lw[4][DEG_CAPW * NHEAD];
    int wave = threadIdx.x >> 6, lane = threadIdx.x & 63;
    float* lwW = lw[wave];
    int n = blockIdx.x * 4 + wave;     // grid = NN/4 exactly (NN%4==0)
    int start = row_ptr[n];
    int deg = row_ptr[n + 1] - start;
    int degc = deg < DEG_CAPW ? deg : DEG_CAPW;
    int hh1 = lane & 7;
    float edv = ed[n * 8 + hh1];

    // pass 1: online per-head softmax stats; stash logits (idx = k*8+head)
    float pm = -1e30f, ps = 0.f;
    for (int idx = lane; idx < deg * 8; idx += 64) {
        int s = srcs[start + (idx >> 3)];
        float e = es[s * 8 + hh1] + edv;
        e = e > 0.f ? e : 0.2f * e;
        if (idx < DEG_CAPW * 8) lwW[idx] = e;
        float mn = fmaxf(pm, e);
        ps = ps * __expf(pm - mn) + __expf(e - mn);
        pm = mn;
    }
#pragma unroll
    for (int off = 8; off <= 32; off <<= 1) {
        float mo = __shfl_xor(pm, off);
        float so = __shfl_xor(ps, off);
        float mn = fmaxf(pm, mo);
        ps = ps * __expf(pm - mn) + so * __expf(mo - mn);
        pm = mn;
    }
    float invd = 1.0f / ps;

    // fixup: slab logit -> normalized alpha (lane idx&7 == hh1)
    int m8 = degc * 8;
    for (int idx = lane; idx < m8; idx += 64)
        lwW[idx] = __expf(lwW[idx] - pm) * invd;
    __builtin_amdgcn_wave_barrier();
    __asm__ volatile("s_waitcnt lgkmcnt(0)" ::: "memory");

    // remap per-head state to pass-2 lane roles (for fallback only)
    int g = lane / TPR;
    int sub = lane & (TPR - 1);
    int c0 = sub * 8;
    int hh = c0 / C;                   // head of this lane's channel chunk
    float mh3 = __shfl(pm, hh);
    float iv3 = __shfl(invd, hh);
    float ed3 = __shfl(edv, hh);

    float acc[8];
#pragma unroll
    for (int j = 0; j < 8; j++) acc[j] = 0.f;

    // pass 2: U*EPI edges in flight
    int k = g;
    for (; k + (U - 1) * EPI < degc; k += U * EPI) {
        int ss[U];
        float ww[U];
#pragma unroll
        for (int u = 0; u < U; u++) {
            ss[u] = srcs[start + k + u * EPI];
            ww[u] = lwW[(k + u * EPI) * 8 + hh];
        }
        uintx4 hv[U];
#pragma unroll
        for (int u = 0; u < U; u++)
            hv[u] = *(const uintx4*)&h[(size_t)ss[u] * HC + c0];
#pragma unroll
        for (int u = 0; u < U; u++) {
#pragma unroll
            for (int j = 0; j < 4; j++) {
                acc[2 * j]     = fmaf(ww[u], bf2f_lo(hv[u][j]), acc[2 * j]);
                acc[2 * j + 1] = fmaf(ww[u], bf2f_hi(hv[u][j]), acc[2 * j + 1]);
            }
        }
    }
    for (; k < degc; k += EPI) {
        int s = srcs[start + k];
        float wv = lwW[k * 8 + hh];
        uintx4 hv = *(const uintx4*)&h[(size_t)s * HC + c0];
#pragma unroll
        for (int j = 0; j < 4; j++) {
            acc[2 * j]     = fmaf(wv, bf2f_lo(hv[j]), acc[2 * j]);
            acc[2 * j + 1] = fmaf(wv, bf2f_hi(hv[j]), acc[2 * j + 1]);
        }
    }
    if (deg > DEG_CAPW) {              // exact fallback (not taken here)
        for (int kk = DEG_CAPW + g; kk < deg; kk += EPI) {
            int s = srcs[start + kk];
            float e = es[s * 8 + hh] + ed3;
            e = e > 0.f ? e : 0.2f * e;
            float wv = __expf(e - mh3) * iv3;
            uintx4 hv = *(const uintx4*)&h[(size_t)s * HC + c0];
#pragma unroll
            for (int j = 0; j < 4; j++) {
                acc[2 * j]     = fmaf(wv, bf2f_lo(hv[j]), acc[2 * j]);
                acc[2 * j + 1] = fmaf(wv, bf2f_hi(hv[j]), acc[2 * j + 1]);
            }
        }
    }
    if (EPI >= 2) {
#pragma unroll
        for (int j = 0; j < 8; j++) acc[j] += __shfl_xor(acc[j], 32);
    }
    if (EPI == 4) {
#pragma unroll
        for (int j = 0; j < 8; j++) acc[j] += __shfl_xor(acc[j], 16);
    }
    if (lane < TPR) {
        floatx4 b0 = *(const floatx4*)&bias[c0];
        floatx4 b1 = *(const floatx4*)&bias[c0 + 4];
        float bb[8] = {b0[0], b0[1], b0[2], b0[3], b1[0], b1[1], b1[2], b1[3]};
        unsigned pk[4];
#pragma unroll
        for (int j = 0; j < 4; j++) {
            float o0 = acc[2 * j] + bb[2 * j];
            float o1 = acc[2 * j + 1] + bb[2 * j + 1];
            if (ELU) {
                o0 = o0 > 0.f ? o0 : (__expf(o0) - 1.0f);
                o1 = o1 > 0.f ? o1 : (__expf(o1) - 1.0f);
            }
            pk[j] = ((unsigned)(unsigned short)f2bf(o0)) |
                    (((unsigned)(unsigned short)f2bf(o1)) << 16);
        }
        *(uintx4*)&out[(size_t)n * HC + c0] = *(uintx4*)pk;
    }
}

// ---------------------------------------------------------------------------
// Global mean pool: 64 graphs x 8 feature-chunks of 64; 4 row stripes/block.
// ---------------------------------------------------------------------------
__global__ __launch_bounds__(256) void pool_kernel(const short* __restrict__ h,
                                                   const int* __restrict__ batch,
                                                   float* __restrict__ gout) {
    __shared__ float red[256];
    int g = blockIdx.x >> 3;
    int fc = (blockIdx.x & 7) * 64;
    int lo = 0, hi = NN;
    while (lo < hi) { int mid = (lo + hi) >> 1; if (batch[mid] < g) lo = mid + 1; else hi = mid; }
    int s = lo;
    lo = 0; hi = NN;
    while (lo < hi) { int mid = (lo + hi) >> 1; if (batch[mid] < g + 1) lo = mid + 1; else hi = mid; }
    int e = lo;
    int t = threadIdx.x;
    int f = t & 63, stripe = t >> 6;
    float a = 0.f;
    for (int r = s + stripe; r < e; r += 4)
        a += bf2f(h[(size_t)r * 512 + fc + f]);
    red[t] = a;
    __syncthreads();
    if (t < 128) red[t] += red[t + 128];
    __syncthreads();
    if (t < 64) {
        float inv = 1.0f / fmaxf((float)(e - s), 1.0f);
        gout[g * 512 + fc + t] = (red[t] + red[t + 64]) * inv;
    }
}

// ---------------------------------------------------------------------------
// Final MLP: [64,512] -> elu(@lw1^T+lb1) -> @lw2^T+lb2 -> [64,2]
// ---------------------------------------------------------------------------
__global__ __launch_bounds__(64) void mlp_kernel(const float* __restrict__ g,
                                                 const float* __restrict__ lw1,
                                                 const float* __restrict__ lb1,
                                                 const float* __restrict__ lw2,
                                                 const float* __restrict__ lb2,
                                                 float* __restrict__ outp) {
    __shared__ float gv[512];
    __shared__ float y1[32];
    int b = blockIdx.x, t = threadIdx.x;
    for (int i = t; i < 512; i += 64) gv[i] = g[b * 512 + i];
    __syncthreads();
    if (t < 32) {
        float a = lb1[t];
        for (int k = 0; k < 512; k++) a = fmaf(gv[k], lw1[t * 512 + k], a);
        y1[t] = a > 0.f ? a : (__expf(a) - 1.0f);
    }
    __syncthreads();
    if (t < 2) {
        float a = lb2[t];
        for (int k = 0; k < 32; k++) a = fmaf(y1[k], lw2[t * 32 + k], a);
        outp[b * 2 + t] = a;
    }
}

// ---------------------------------------------------------------------------
// Launch
// ---------------------------------------------------------------------------
extern "C" void kernel_launch(void* const* d_in, const int* in_sizes, int n_in,
                              void* d_out, int out_size, void* d_ws, size_t ws_size,
                              hipStream_t stream) {
    (void)in_sizes; (void)n_in; (void)out_size; (void)ws_size;
    const float* x     = (const float*)d_in[0];
    const int*   ei    = (const int*)d_in[1];
    const int*   batch = (const int*)d_in[2];
    const float* W[4]  = {(const float*)d_in[3], (const float*)d_in[7],
                          (const float*)d_in[11], (const float*)d_in[15]};
    const float* As_[4] = {(const float*)d_in[4], (const float*)d_in[8],
                           (const float*)d_in[12], (const float*)d_in[16]};
    const float* Ad_[4] = {(const float*)d_in[5], (const float*)d_in[9],
                           (const float*)d_in[13], (const float*)d_in[17]};
    const float* Bi[4]  = {(const float*)d_in[6], (const float*)d_in[10],
                           (const float*)d_in[14], (const float*)d_in[18]};
    const float* lw1 = (const float*)d_in[19];
    const float* lb1 = (const float*)d_in[20];
    const float* lw2 = (const float*)d_in[21];
    const float* lb2 = (const float*)d_in[22];
    float* out = (float*)d_out;

    // workspace layout (bf16 buffers as short)
    short* Ab = (short*)d_ws;                      // [MPAD*512] activations
    short* Hb = Ab + (size_t)MPAD * 512;           // [MPAD*512] h = act @ W^T
    short* Wb = Hb + (size_t)MPAD * 512;           // bf16 weights
    short* Wb_[4] = {Wb, Wb + 65536, Wb + 196608, Wb + 229376};
    const int wsz[4] = {65536, 131072, 32768, 65536};
    float* esb  = (float*)(Wb + 294912);           // [NN*8]
    float* edb  = esb + NN * NHEAD;                // [NN*8]
    float* gbuf = edb + NN * NHEAD;                // [64*512]
    int* row_ptr = (int*)(gbuf + NGR * 512);       // [NN+1]
    int* cursor  = row_ptr + (NN + 1);             // [NN+1]
    int* srcs    = cursor + (NN + 1);              // [NEP]
    int* bsum    = srcs + NEP;                     // [64]

    const int nblk = (NN + 1023) / 1024;           // 49

    // ---- CSR build (shared by all 4 layers)
    hipMemsetAsync(cursor, 0, NN * sizeof(int), stream);
    count_deg<<<(NEP + 255) / 256, 256, 0, stream>>>(ei, cursor);
    scan_local<<<nblk, 1024, 0, stream>>>(cursor, row_ptr, bsum, NN);
    scan_bsum<<<1, 64, 0, stream>>>(bsum, nblk);
    scan_add<<<(NN + 256) / 256, 256, 0, stream>>>(row_ptr, cursor, bsum, NN, nblk);
    scatter_edges<<<(NEP + 255) / 256, 256, 0, stream>>>(ei, cursor, srcs);

    // ---- bf16 conversions
    conv_x_pad4<<<(MPAD * 32 + 255) / 256, 256, 0, stream>>>(x, Ab);
    for (int i = 0; i < 4; i++)
        conv_f2bf<<<(wsz[i] + 255) / 256, 256, 0, stream>>>(W[i], Wb_[i], wsz[i]);

    const int rowTiles = MPAD / 128;               // 391
    const int ag = NN / 4;                         // 12500 blocks, 4 nodes each

    // ---- layer 1: 128 -> 512 (C=64), ELU
    gemm_bf<64><<<rowTiles * 4, 256, 0, stream>>>(Ab, Wb_[0], Hb, As_[0], Ad_[0], esb, edb, 128);
    attn_wave<64, true><<<ag, 256, 0, stream>>>(Hb, esb, edb, row_ptr, srcs, Bi[0], Ab);

    // ---- layer 2: 512 -> 256 (C=32), ELU
    gemm_bf<32><<<rowTiles * 2, 256, 0, stream>>>(Ab, Wb_[1], Hb, As_[1], Ad_[1], esb, edb, 512);
    attn_wave<32, true><<<ag, 256, 0, stream>>>(Hb, esb, edb, row_ptr, srcs, Bi[1], Ab);

    // ---- layer 3: 256 -> 128 (C=16), ELU
    gemm_bf<16><<<rowTiles * 1, 256, 0, stream>>>(Ab, Wb_[2], Hb, As_[2], Ad_[2], esb, edb, 256);
    attn_wave<16, true><<<ag, 256, 0, stream>>>(Hb, esb, edb, row_ptr, srcs, Bi[2], Ab);

    // ---- layer 4: 128 -> 512 (C=64), no ELU
    gemm_bf<64><<<rowTiles * 4, 256, 0, stream>>>(Ab, Wb_[3], Hb, As_[3], Ad_[3], esb, edb, 128);
    attn_wave<64, false><<<ag, 256, 0, stream>>>(Hb, esb, edb, row_ptr, srcs, Bi[3], Ab);

    // ---- pool + MLP
    pool_kernel<<<NGR * 8, 256, 0, stream>>>(Ab, batch, gbuf);
    mlp_kernel<<<NGR, 64, 0, stream>>>(gbuf, lw1, lb1, lw2, lb2, out);
}

// Round 11
// 753.613 us; speedup vs baseline: 1.0946x; 1.0645x over previous
//
#include <hip/hip_runtime.h>
#include <math.h>

// ---------------------------------------------------------------------------
// Problem constants
// ---------------------------------------------------------------------------
#define NN 50000          // nodes
#define NE 800000         // edges (before self loops)
#define NEP (NE + NN)     // edges incl self loops
#define NGR 64            // graphs
#define NHEAD 8
#define MPAD 50048        // 391 * 128
#define DEG_CAPW 128      // per-wave LDS alpha slab (edges); exact fallback beyond

typedef short short8 __attribute__((ext_vector_type(8)));
typedef float floatx4 __attribute__((ext_vector_type(4)));
typedef unsigned uintx4 __attribute__((ext_vector_type(4)));

__device__ inline float bf2f(short s) {
    union { unsigned u; float f; } v;
    v.u = ((unsigned)(unsigned short)s) << 16;
    return v.f;
}
__device__ inline float bf2f_lo(unsigned p) {
    union { unsigned u; float f; } v; v.u = p << 16; return v.f;
}
__device__ inline float bf2f_hi(unsigned p) {
    union { unsigned u; float f; } v; v.u = p & 0xffff0000u; return v.f;
}
__device__ inline short f2bf(float f) {
    union { float f; unsigned u; } v; v.f = f;
    unsigned r = v.u + 0x7fffu + ((v.u >> 16) & 1u);   // RNE
    return (short)(r >> 16);
}

// async global->LDS, 16 B per lane; lds dst = wave-uniform base + lane*16
__device__ inline void gl_lds16(const short* g, short* l) {
    __builtin_amdgcn_global_load_lds(
        (const __attribute__((address_space(1))) unsigned int*)g,
        (__attribute__((address_space(3))) unsigned int*)l, 16, 0, 0);
}

// ---------------------------------------------------------------------------
// CSR build (dst-major). Edge e<NE: src=ei[e], dst=ei[NE+e]; else self loop.
// ---------------------------------------------------------------------------
__global__ void count_deg(const int* __restrict__ ei, int* __restrict__ deg) {
    int e = blockIdx.x * 256 + threadIdx.x;
    if (e >= NEP) return;
    int d = (e < NE) ? ei[NE + e] : (e - NE);
    atomicAdd(&deg[d], 1);
}

__global__ __launch_bounds__(1024) void scan_local(const int* __restrict__ deg,
                                                   int* __restrict__ out,
                                                   int* __restrict__ bsum, int n) {
    __shared__ int sd[1024];
    int b = blockIdx.x, t = threadIdx.x;
    int i = b * 1024 + t;
    int v = (i < n) ? deg[i] : 0;
    sd[t] = v;
    __syncthreads();
    for (int off = 1; off < 1024; off <<= 1) {
        int tmp = (t >= off) ? sd[t - off] : 0;
        __syncthreads();
        sd[t] += tmp;
        __syncthreads();
    }
    if (i < n) out[i] = sd[t] - v;          // exclusive
    if (t == 1023) bsum[b] = sd[1023];
}

__global__ void scan_bsum(int* __restrict__ bsum, int nb) {
    if (threadIdx.x == 0) {
        int s = 0;
        for (int i = 0; i < nb; i++) { int v = bsum[i]; bsum[i] = s; s += v; }
        bsum[nb] = s;
    }
}

__global__ void scan_add(int* __restrict__ row_ptr, int* __restrict__ cursor,
                         const int* __restrict__ bsum, int n, int nb) {
    int i = blockIdx.x * 256 + threadIdx.x;
    if (i < n) {
        int v = row_ptr[i] + bsum[i >> 10];
        row_ptr[i] = v;
        cursor[i] = v;
    } else if (i == n) {
        row_ptr[n] = bsum[nb];
    }
}

__global__ void scatter_edges(const int* __restrict__ ei, int* __restrict__ cursor,
                              int* __restrict__ srcs) {
    int e = blockIdx.x * 256 + threadIdx.x;
    if (e >= NEP) return;
    int s, d;
    if (e < NE) { s = ei[e]; d = ei[NE + e]; }
    else        { s = e - NE; d = e - NE; }
    int pos = atomicAdd(&cursor[d], 1);
    srcs[pos] = s;
}

// ---------------------------------------------------------------------------
// fp32 -> bf16 conversions
// ---------------------------------------------------------------------------
// all 4 weight matrices in one launch (dst layout is contiguous)
__global__ void conv_w_all(const float* __restrict__ w0, const float* __restrict__ w1,
                           const float* __restrict__ w2, const float* __restrict__ w3,
                           short* __restrict__ out) {
    int i = blockIdx.x * 256 + threadIdx.x;          // 0 .. 294911
    if (i >= 294912) return;
    const float* src; int off;
    if (i < 65536)       { src = w0; off = i; }
    else if (i < 196608) { src = w1; off = i - 65536; }
    else if (i < 229376) { src = w2; off = i - 196608; }
    else                 { src = w3; off = i - 229376; }
    out[i] = f2bf(src[off]);
}

__global__ void conv_x_pad4(const float* __restrict__ x, short* __restrict__ xb) {
    int i = blockIdx.x * 256 + threadIdx.x;          // one float4 per thread
    if (i >= MPAD * 32) return;
    int r = i >> 5;
    short4 o;
    if (r < NN) {
        float4 v = *(const float4*)&x[(size_t)i * 4];
        o.x = f2bf(v.x); o.y = f2bf(v.y); o.z = f2bf(v.z); o.w = f2bf(v.w);
    } else {
        o.x = o.y = o.z = o.w = 0;
    }
    *(short4*)&xb[(size_t)i * 4] = o;
}

// ---------------------------------------------------------------------------
// bf16 MFMA GEMM + fused es/ed epilogue, async global_load_lds staging.
// XOR-swizzled unpadded LDS, BK=64, 128x128 tile, 4 waves. (R8 config —
// single-buffered: explicit dbuf measured neutral-negative, R10.)
// ---------------------------------------------------------------------------
template <int C>
__global__ __launch_bounds__(256) void gemm_bf(const short* __restrict__ A,
                                               const short* __restrict__ B,
                                               short* __restrict__ Cout,
                                               const float* __restrict__ a_s,
                                               const float* __restrict__ a_d,
                                               float* __restrict__ es,
                                               float* __restrict__ ed,
                                               int K) {
    constexpr int Nc = 8 * C;
    constexpr int colTiles = Nc / 128;
    constexpr int JPH = C / 16;        // j-frags per head within a wave
    constexpr int HPW = 64 / C;        // heads fully covered by one wave
    __shared__ __align__(16) short As[128 * 64];
    __shared__ __align__(16) short Bs[128 * 64];
    int bx = blockIdx.x % colTiles;
    int by = blockIdx.x / colTiles;
    int row0 = by * 128, col0 = bx * 128;
    int t = threadIdx.x;
    int lane = t & 63, w = t >> 6;
    int wr = (w >> 1) * 64, wc = (w & 1) * 64;
    int lrow = lane & 15, lq = lane >> 4;

    int srow = lane >> 3;              // 0..7 row within 8-row group
    int kcsrc = (lane & 7) ^ srow;     // swizzled source k-chunk

    floatx4 acc[4][4];
#pragma unroll
    for (int i = 0; i < 4; i++)
#pragma unroll
        for (int j = 0; j < 4; j++) acc[i][j] = (floatx4)0.0f;

    for (int k0 = 0; k0 < K; k0 += 64) {
#pragma unroll
        for (int it = 0; it < 4; it++) {
            int r0 = w * 32 + it * 8;
            int r = r0 + srow;
            gl_lds16(&A[(size_t)(row0 + r) * K + k0 + kcsrc * 8], &As[r0 * 64]);
            gl_lds16(&B[(size_t)(col0 + r) * K + k0 + kcsrc * 8], &Bs[r0 * 64]);
        }
        __syncthreads();
#pragma unroll
        for (int kk = 0; kk < 2; kk++) {
            int slot = (kk * 4 + lq) ^ (lrow & 7);
            short8 af[4], bfr[4];
#pragma unroll
            for (int i = 0; i < 4; i++)
                af[i] = *(const short8*)&As[(wr + i * 16 + lrow) * 64 + slot * 8];
#pragma unroll
            for (int j = 0; j < 4; j++)
                bfr[j] = *(const short8*)&Bs[(wc + j * 16 + lrow) * 64 + slot * 8];
#pragma unroll
            for (int i = 0; i < 4; i++)
#pragma unroll
                for (int j = 0; j < 4; j++)
                    acc[i][j] = __builtin_amdgcn_mfma_f32_16x16x32_bf16(af[i], bfr[j], acc[i][j], 0, 0, 0);
        }
        __syncthreads();
    }

    // ---- C store (D layout: row=wr+i*16+lq*4+r, col=wc+j*16+lrow)
#pragma unroll
    for (int i = 0; i < 4; i++)
#pragma unroll
        for (int j = 0; j < 4; j++)
#pragma unroll
            for (int r = 0; r < 4; r++) {
                int row = row0 + wr + i * 16 + lq * 4 + r;
                int col = col0 + wc + j * 16 + lrow;
                Cout[(size_t)row * Nc + col] = f2bf(acc[i][j][r]);
            }

    // ---- fused es/ed epilogue (a_s flat [H*C] == abs col index)
    float asv[4], adv[4];
#pragma unroll
    for (int j = 0; j < 4; j++) {
        int colA = col0 + wc + j * 16 + lrow;
        asv[j] = a_s[colA];
        adv[j] = a_d[colA];
    }
    int hb = (col0 + wc) / C;
#pragma unroll
    for (int i = 0; i < 4; i++)
#pragma unroll
        for (int r = 0; r < 4; r++) {
            float s_h[HPW], d_h[HPW];
#pragma unroll
            for (int hh = 0; hh < HPW; hh++) { s_h[hh] = 0.f; d_h[hh] = 0.f; }
#pragma unroll
            for (int j = 0; j < 4; j++) {
                s_h[j / JPH] = fmaf(acc[i][j][r], asv[j], s_h[j / JPH]);
                d_h[j / JPH] = fmaf(acc[i][j][r], adv[j], d_h[j / JPH]);
            }
#pragma unroll
            for (int hh = 0; hh < HPW; hh++) {
#pragma unroll
                for (int off = 1; off <= 8; off <<= 1) {
                    s_h[hh] += __shfl_xor(s_h[hh], off);
                    d_h[hh] += __shfl_xor(d_h[hh], off);
                }
            }
            if (lrow == 0) {
                int row = row0 + wr + i * 16 + lq * 4 + r;
                if (row < NN) {
#pragma unroll
                    for (int hh = 0; hh < HPW; hh++) {
                        es[row * 8 + hb + hh] = s_h[hh];
                        ed[row * 8 + hb + hh] = d_h[hh];
                    }
                }
            }
        }
}

// ---------------------------------------------------------------------------
// Attention — ONE WAVE PER NODE, wave-synchronous (R8 config: CAPW=128, U=4).
// Pass 1: online softmax, stash leaky-relu logits in per-wave LDS slab.
// Fixup : slab -> normalized alpha in place.
// Pass 2: ds_read alpha + 16B h gather, U*EPI edges in flight.
// Gather plateaus at ~3.8 TB/s across occ 37-76% / ILP 2-8x (R7-R10):
// structural per-XCD L2 compulsory-miss ceiling for random 1KB rows.
// ---------------------------------------------------------------------------
template <int C, bool ELU>
__global__ __launch_bounds__(256) void attn_wave(const short* __restrict__ h,
                                                 const float* __restrict__ es,
                                                 const float* __restrict__ ed,
                                                 const int* __restrict__ row_ptr,
                                                 const int* __restrict__ srcs,
                                                 const float* __restrict__ bias,
                                                 short* __restrict__ out) {
    constexpr int HC = NHEAD * C;
    constexpr int TPR = HC / 8;        // lanes covering one row: 64/32/16
    constexpr int EPI = 64 / TPR;      // edge groups per wave: 1/2/4
    constexpr int U = (EPI == 1) ? 4 : 2;   // unroll: U*EPI loads in flight
    __shared__ float lw[4][DEG_CAPW * NHEAD];
    int wave = threadIdx.x >> 6, lane = threadIdx.x & 63;
    float* lwW = lw[wave];
    int n = blockIdx.x * 4 + wave;     // grid = NN/4 exactly (NN%4==0)
    int start = row_ptr[n];
    int deg = row_ptr[n + 1] - start;
    int degc = deg < DEG_CAPW ? deg : DEG_CAPW;
    int hh1 = lane & 7;
    float edv = ed[n * 8 + hh1];

    // pass 1: online per-head softmax stats; stash logits (idx = k*8+head)
    float pm = -1e30f, ps = 0.f;
    for (int idx = lane; idx < deg * 8; idx += 64) {
        int s = srcs[start + (idx >> 3)];
        float e = es[s * 8 + hh1] + edv;
        e = e > 0.f ? e : 0.2f * e;
        if (idx < DEG_CAPW * 8) lwW[idx] = e;
        float mn = fmaxf(pm, e);
        ps = ps * __expf(pm - mn) + __expf(e - mn);
        pm = mn;
    }
#pragma unroll
    for (int off = 8; off <= 32; off <<= 1) {
        float mo = __shfl_xor(pm, off);
        float so = __shfl_xor(ps, off);
        float mn = fmaxf(pm, mo);
        ps = ps * __expf(pm - mn) + so * __expf(mo - mn);
        pm = mn;
    }
    float invd = 1.0f / ps;

    // fixup: slab logit -> normalized alpha (lane idx&7 == hh1)
    int m8 = degc * 8;
    for (int idx = lane; idx < m8; idx += 64)
        lwW[idx] = __expf(lwW[idx] - pm) * invd;
    __builtin_amdgcn_wave_barrier();
    __asm__ volatile("s_waitcnt lgkmcnt(0)" ::: "memory");

    // remap per-head state to pass-2 lane roles (for fallback only)
    int g = lane / TPR;
    int sub = lane & (TPR - 1);
    int c0 = sub * 8;
    int hh = c0 / C;                   // head of this lane's channel chunk
    float mh3 = __shfl(pm, hh);
    float iv3 = __shfl(invd, hh);
    float ed3 = __shfl(edv, hh);

    float acc[8];
#pragma unroll
    for (int j = 0; j < 8; j++) acc[j] = 0.f;

    // pass 2: U*EPI edges in flight
    int k = g;
    for (; k + (U - 1) * EPI < degc; k += U * EPI) {
        int ss[U];
        float ww[U];
#pragma unroll
        for (int u = 0; u < U; u++) {
            ss[u] = srcs[start + k + u * EPI];
            ww[u] = lwW[(k + u * EPI) * 8 + hh];
        }
        uintx4 hv[U];
#pragma unroll
        for (int u = 0; u < U; u++)
            hv[u] = *(const uintx4*)&h[(size_t)ss[u] * HC + c0];
#pragma unroll
        for (int u = 0; u < U; u++) {
#pragma unroll
            for (int j = 0; j < 4; j++) {
                acc[2 * j]     = fmaf(ww[u], bf2f_lo(hv[u][j]), acc[2 * j]);
                acc[2 * j + 1] = fmaf(ww[u], bf2f_hi(hv[u][j]), acc[2 * j + 1]);
            }
        }
    }
    for (; k < degc; k += EPI) {
        int s = srcs[start + k];
        float wv = lwW[k * 8 + hh];
        uintx4 hv = *(const uintx4*)&h[(size_t)s * HC + c0];
#pragma unroll
        for (int j = 0; j < 4; j++) {
            acc[2 * j]     = fmaf(wv, bf2f_lo(hv[j]), acc[2 * j]);
            acc[2 * j + 1] = fmaf(wv, bf2f_hi(hv[j]), acc[2 * j + 1]);
        }
    }
    if (deg > DEG_CAPW) {              // exact fallback (not taken here)
        for (int kk = DEG_CAPW + g; kk < deg; kk += EPI) {
            int s = srcs[start + kk];
            float e = es[s * 8 + hh] + ed3;
            e = e > 0.f ? e : 0.2f * e;
            float wv = __expf(e - mh3) * iv3;
            uintx4 hv = *(const uintx4*)&h[(size_t)s * HC + c0];
#pragma unroll
            for (int j = 0; j < 4; j++) {
                acc[2 * j]     = fmaf(wv, bf2f_lo(hv[j]), acc[2 * j]);
                acc[2 * j + 1] = fmaf(wv, bf2f_hi(hv[j]), acc[2 * j + 1]);
            }
        }
    }
    if (EPI >= 2) {
#pragma unroll
        for (int j = 0; j < 8; j++) acc[j] += __shfl_xor(acc[j], 32);
    }
    if (EPI == 4) {
#pragma unroll
        for (int j = 0; j < 8; j++) acc[j] += __shfl_xor(acc[j], 16);
    }
    if (lane < TPR) {
        floatx4 b0 = *(const floatx4*)&bias[c0];
        floatx4 b1 = *(const floatx4*)&bias[c0 + 4];
        float bb[8] = {b0[0], b0[1], b0[2], b0[3], b1[0], b1[1], b1[2], b1[3]};
        unsigned pk[4];
#pragma unroll
        for (int j = 0; j < 4; j++) {
            float o0 = acc[2 * j] + bb[2 * j];
            float o1 = acc[2 * j + 1] + bb[2 * j + 1];
            if (ELU) {
                o0 = o0 > 0.f ? o0 : (__expf(o0) - 1.0f);
                o1 = o1 > 0.f ? o1 : (__expf(o1) - 1.0f);
            }
            pk[j] = ((unsigned)(unsigned short)f2bf(o0)) |
                    (((unsigned)(unsigned short)f2bf(o1)) << 16);
        }
        *(uintx4*)&out[(size_t)n * HC + c0] = *(uintx4*)pk;
    }
}

// ---------------------------------------------------------------------------
// Global mean pool: 64 graphs x 8 chunks of 64 ch; 16B/lane loads,
// shfl stripe-reduce within wave, tiny LDS combine across 4 waves.
// ---------------------------------------------------------------------------
__global__ __launch_bounds__(256) void pool_kernel(const short* __restrict__ h,
                                                   const int* __restrict__ batch,
                                                   float* __restrict__ gout) {
    __shared__ float red[4 * 64];
    int g = blockIdx.x >> 3;
    int fc = (blockIdx.x & 7) * 64;
    int lo = 0, hi = NN;
    while (lo < hi) { int mid = (lo + hi) >> 1; if (batch[mid] < g) lo = mid + 1; else hi = mid; }
    int s = lo;
    lo = 0; hi = NN;
    while (lo < hi) { int mid = (lo + hi) >> 1; if (batch[mid] < g + 1) lo = mid + 1; else hi = mid; }
    int e = lo;
    int t = threadIdx.x;
    int wave = t >> 6, lane = t & 63;
    int f8 = (lane & 7) * 8;           // 8 channels per lane within the 64-chunk
    int stripe = wave * 8 + (lane >> 3);   // 0..31 row stripes
    float acc[8];
#pragma unroll
    for (int j = 0; j < 8; j++) acc[j] = 0.f;
    for (int r = s + stripe; r < e; r += 32) {
        short8 v = *(const short8*)&h[(size_t)r * 512 + fc + f8];
#pragma unroll
        for (int j = 0; j < 8; j++) acc[j] += bf2f(v[j]);
    }
    // reduce 8 stripes within the wave (lane bits 3,4,5)
#pragma unroll
    for (int j = 0; j < 8; j++) {
        acc[j] += __shfl_xor(acc[j], 8);
        acc[j] += __shfl_xor(acc[j], 16);
        acc[j] += __shfl_xor(acc[j], 32);
    }
    if (lane < 8) {
#pragma unroll
        for (int j = 0; j < 8; j++) red[wave * 64 + lane * 8 + j] = acc[j];
    }
    __syncthreads();
    if (t < 64) {                      // t = ch within chunk
        float v = red[t] + red[64 + t] + red[128 + t] + red[192 + t];
        float inv = 1.0f / fmaxf((float)(e - s), 1.0f);
        gout[g * 512 + fc + t] = v * inv;
    }
}

// ---------------------------------------------------------------------------
// Final MLP: [64,512] -> elu(@lw1^T+lb1) -> @lw2^T+lb2 -> [64,2]
// ---------------------------------------------------------------------------
__global__ __launch_bounds__(64) void mlp_kernel(const float* __restrict__ g,
                                                 const float* __restrict__ lw1,
                                                 const float* __restrict__ lb1,
                                                 const float* __restrict__ lw2,
                                                 const float* __restrict__ lb2,
                                                 float* __restrict__ outp) {
    __shared__ float gv[512];
    __shared__ float y1[32];
    int b = blockIdx.x, t = threadIdx.x;
    for (int i = t; i < 512; i += 64) gv[i] = g[b * 512 + i];
    __syncthreads();
    if (t < 32) {
        float a = lb1[t];
        for (int k = 0; k < 512; k++) a = fmaf(gv[k], lw1[t * 512 + k], a);
        y1[t] = a > 0.f ? a : (__expf(a) - 1.0f);
    }
    __syncthreads();
    if (t < 2) {
        float a = lb2[t];
        for (int k = 0; k < 32; k++) a = fmaf(y1[k], lw2[t * 32 + k], a);
        outp[b * 2 + t] = a;
    }
}

// ---------------------------------------------------------------------------
// Launch
// ---------------------------------------------------------------------------
extern "C" void kernel_launch(void* const* d_in, const int* in_sizes, int n_in,
                              void* d_out, int out_size, void* d_ws, size_t ws_size,
                              hipStream_t stream) {
    (void)in_sizes; (void)n_in; (void)out_size; (void)ws_size;
    const float* x     = (const float*)d_in[0];
    const int*   ei    = (const int*)d_in[1];
    const int*   batch = (const int*)d_in[2];
    const float* W[4]  = {(const float*)d_in[3], (const float*)d_in[7],
                          (const float*)d_in[11], (const float*)d_in[15]};
    const float* As_[4] = {(const float*)d_in[4], (const float*)d_in[8],
                           (const float*)d_in[12], (const float*)d_in[16]};
    const float* Ad_[4] = {(const float*)d_in[5], (const float*)d_in[9],
                           (const float*)d_in[13], (const float*)d_in[17]};
    const float* Bi[4]  = {(const float*)d_in[6], (const float*)d_in[10],
                           (const float*)d_in[14], (const float*)d_in[18]};
    const float* lw1 = (const float*)d_in[19];
    const float* lb1 = (const float*)d_in[20];
    const float* lw2 = (const float*)d_in[21];
    const float* lb2 = (const float*)d_in[22];
    float* out = (float*)d_out;

    // workspace layout (bf16 buffers as short)
    short* Ab = (short*)d_ws;                      // [MPAD*512] activations
    short* Hb = Ab + (size_t)MPAD * 512;           // [MPAD*512] h = act @ W^T
    short* Wb = Hb + (size_t)MPAD * 512;           // bf16 weights (contiguous)
    short* Wb_[4] = {Wb, Wb + 65536, Wb + 196608, Wb + 229376};
    float* esb  = (float*)(Wb + 294912);           // [NN*8]
    float* edb  = esb + NN * NHEAD;                // [NN*8]
    float* gbuf = edb + NN * NHEAD;                // [64*512]
    int* row_ptr = (int*)(gbuf + NGR * 512);       // [NN+1]
    int* cursor  = row_ptr + (NN + 1);             // [NN+1]
    int* srcs    = cursor + (NN + 1);              // [NEP]
    int* bsum    = srcs + NEP;                     // [64]

    const int nblk = (NN + 1023) / 1024;           // 49

    // ---- CSR build (shared by all 4 layers)
    hipMemsetAsync(cursor, 0, NN * sizeof(int), stream);
    count_deg<<<(NEP + 255) / 256, 256, 0, stream>>>(ei, cursor);
    scan_local<<<nblk, 1024, 0, stream>>>(cursor, row_ptr, bsum, NN);
    scan_bsum<<<1, 64, 0, stream>>>(bsum, nblk);
    scan_add<<<(NN + 256) / 256, 256, 0, stream>>>(row_ptr, cursor, bsum, NN, nblk);
    scatter_edges<<<(NEP + 255) / 256, 256, 0, stream>>>(ei, cursor, srcs);

    // ---- bf16 conversions
    conv_x_pad4<<<(MPAD * 32 + 255) / 256, 256, 0, stream>>>(x, Ab);
    conv_w_all<<<(294912 + 255) / 256, 256, 0, stream>>>(W[0], W[1], W[2], W[3], Wb);

    const int rowTiles = MPAD / 128;               // 391
    const int ag = NN / 4;                         // 12500 blocks, 4 nodes each

    // ---- layer 1: 128 -> 512 (C=64), ELU
    gemm_bf<64><<<rowTiles * 4, 256, 0, stream>>>(Ab, Wb_[0], Hb, As_[0], Ad_[0], esb, edb, 128);
    attn_wave<64, true><<<ag, 256, 0, stream>>>(Hb, esb, edb, row_ptr, srcs, Bi[0], Ab);

    // ---- layer 2: 512 -> 256 (C=32), ELU
    gemm_bf<32><<<rowTiles * 2, 256, 0, stream>>>(Ab, Wb_[1], Hb, As_[1], Ad_[1], esb, edb, 512);
    attn_wave<32, true><<<ag, 256, 0, stream>>>(Hb, esb, edb, row_ptr, srcs, Bi[1], Ab);

    // ---- layer 3: 256 -> 128 (C=16), ELU
    gemm_bf<16><<<rowTiles * 1, 256, 0, stream>>>(Ab, Wb_[2], Hb, As_[2], Ad_[2], esb, edb, 256);
    attn_wave<16, true><<<ag, 256, 0, stream>>>(Hb, esb, edb, row_ptr, srcs, Bi[2], Ab);

    // ---- layer 4: 128 -> 512 (C=64), no ELU
    gemm_bf<64><<<rowTiles * 4, 256, 0, stream>>>(Ab, Wb_[3], Hb, As_[3], Ad_[3], esb, edb, 128);
    attn_wave<64, false><<<ag, 256, 0, stream>>>(Hb, esb, edb, row_ptr, srcs, Bi[3], Ab);

    // ---- pool + MLP
    pool_kernel<<<NGR * 8, 256, 0, stream>>>(Ab, batch, gbuf);
    mlp_kernel<<<NGR, 64, 0, stream>>>(gbuf, lw1, lb1, lw2, lb2, out);
}